// Round 1
// baseline (238.761 us; speedup 1.0000x reference)
//
#include <hip/hip_runtime.h>
#include <hip/hip_bf16.h>

#define IMG_H 512
#define IMG_W 512
#define NB 32
#define NC 3
#define TILE_W 64
#define TILE_H 16
#define LDS_W (TILE_W + 2)   // 66
#define LDS_H (TILE_H + 2)   // 18

// Kernel 1: gray = mean(ch), Sobel magnitude -> out[b][0][:,:], per-image max -> maxbuf[b]
__global__ __launch_bounds__(256) void sobel_mag_kernel(
    const float* __restrict__ in, float* __restrict__ out,
    unsigned int* __restrict__ maxbuf)
{
    __shared__ float g[LDS_H][LDS_W];
    __shared__ float wmax[4];

    const int b   = blockIdx.z;
    const int tx0 = blockIdx.x * TILE_W;
    const int ty0 = blockIdx.y * TILE_H;
    const int tid = threadIdx.y * 64 + threadIdx.x;   // block = (64,4)

    const size_t HW = (size_t)IMG_H * IMG_W;
    const float* base = in + (size_t)b * NC * HW;

    // Cooperative load of gray tile with 1-px halo (zero padding at borders).
    for (int idx = tid; idx < LDS_H * LDS_W; idx += 256) {
        int ly = idx / LDS_W;
        int lx = idx - ly * LDS_W;
        int gy = ty0 + ly - 1;
        int gx = tx0 + lx - 1;
        float v = 0.0f;
        if (gy >= 0 && gy < IMG_H && gx >= 0 && gx < IMG_W) {
            int o = gy * IMG_W + gx;
            v = (base[o] + base[HW + o] + base[2 * HW + o]) * (1.0f / 3.0f);
        }
        g[ly][lx] = v;
    }
    __syncthreads();

    float lmax = 0.0f;
    float* outb = out + (size_t)b * NC * HW;   // channel-0 plane used as magnitude scratch

    #pragma unroll
    for (int r = 0; r < TILE_H / 4; ++r) {
        const int ly = threadIdx.y + r * 4;     // local row in [0, TILE_H)
        const int lx = threadIdx.x;             // local col in [0, TILE_W)
        // 3x3 neighborhood; center at g[ly+1][lx+1]
        float a00 = g[ly][lx],     a01 = g[ly][lx + 1],     a02 = g[ly][lx + 2];
        float a10 = g[ly + 1][lx],                          a12 = g[ly + 1][lx + 2];
        float a20 = g[ly + 2][lx], a21 = g[ly + 2][lx + 1], a22 = g[ly + 2][lx + 2];
        float sx = (a02 - a00) + 2.0f * (a12 - a10) + (a22 - a20);
        float sy = (a20 - a00) + 2.0f * (a21 - a01) + (a22 - a02);
        float mag = sqrtf(sx * sx + sy * sy);
        outb[(size_t)(ty0 + ly) * IMG_W + (tx0 + lx)] = mag;
        lmax = fmaxf(lmax, mag);
    }

    // Wave (64-lane) shuffle reduce, then 4-wave LDS reduce, then device atomicMax.
    #pragma unroll
    for (int off = 32; off > 0; off >>= 1)
        lmax = fmaxf(lmax, __shfl_down(lmax, off, 64));
    if ((tid & 63) == 0) wmax[tid >> 6] = lmax;
    __syncthreads();
    if (tid == 0) {
        float m = fmaxf(fmaxf(wmax[0], wmax[1]), fmaxf(wmax[2], wmax[3]));
        // magnitude >= 0, so uint bit-pattern ordering == float ordering
        atomicMax(&maxbuf[b], __float_as_uint(m));
    }
}

// Kernel 2: read magnitude from channel 0, normalize, broadcast to all 3 channels.
__global__ __launch_bounds__(256) void normalize_kernel(
    float* __restrict__ out, const unsigned int* __restrict__ maxbuf)
{
    const size_t HW  = (size_t)IMG_H * IMG_W;
    const size_t HW4 = HW / 4;                 // 65536 float4 per plane
    const size_t total = (size_t)NB * HW4;

    for (size_t i = (size_t)blockIdx.x * blockDim.x + threadIdx.x;
         i < total; i += (size_t)gridDim.x * blockDim.x) {
        const int    b   = (int)(i >> 16);     // i / 65536
        const size_t hw4 = i & (HW4 - 1);      // i % 65536

        float  mx  = __uint_as_float(maxbuf[b]);
        float  inv = 1.0f / (mx + 1e-6f);

        float4* c0 = (float4*)(out + (size_t)b * NC * HW) + hw4;
        float4* c1 = (float4*)(out + ((size_t)b * NC + 1) * HW) + hw4;
        float4* c2 = (float4*)(out + ((size_t)b * NC + 2) * HW) + hw4;

        float4 m = *c0;
        float4 v = make_float4(m.x * inv, m.y * inv, m.z * inv, m.w * inv);
        *c0 = v;
        *c1 = v;
        *c2 = v;
    }
}

extern "C" void kernel_launch(void* const* d_in, const int* in_sizes, int n_in,
                              void* d_out, int out_size, void* d_ws, size_t ws_size,
                              hipStream_t stream)
{
    const float* in  = (const float*)d_in[0];
    float*       out = (float*)d_out;
    unsigned int* maxbuf = (unsigned int*)d_ws;   // 32 * 4 = 128 bytes

    // zero per-image max accumulators (0x00000000 == 0.0f)
    hipMemsetAsync(maxbuf, 0, NB * sizeof(unsigned int), stream);

    dim3 grid1(IMG_W / TILE_W, IMG_H / TILE_H, NB);   // (8, 32, 32)
    dim3 blk1(64, 4, 1);
    sobel_mag_kernel<<<grid1, blk1, 0, stream>>>(in, out, maxbuf);

    dim3 grid2(2048, 1, 1);
    dim3 blk2(256, 1, 1);
    normalize_kernel<<<grid2, blk2, 0, stream>>>(out, maxbuf);
}

// Round 2
// 215.196 us; speedup vs baseline: 1.1095x; 1.1095x over previous
//
#include <hip/hip_runtime.h>
#include <hip/hip_bf16.h>

#define IMG_H 512
#define IMG_W 512
#define NB 32
#define NC 3
#define TILE_W 128
#define TILE_H 16
#define LDS_ROWS (TILE_H + 2)        // 18
#define LDS_F4_W 34                  // f4 per LDS row: covers x0-4 .. x0+131
#define LDS_F_W  (LDS_F4_W * 4)      // 136 floats
#define PLANE_F4 65536               // 512*512/4

// Kernel 1: gray = mean(ch), Sobel magnitude -> out[b][0][:,:], per-image max -> maxbuf[b]
__global__ __launch_bounds__(256) void sobel_mag_kernel(
    const float* __restrict__ in, float* __restrict__ out,
    unsigned int* __restrict__ maxbuf)
{
    __shared__ float4 g4[LDS_ROWS * LDS_F4_W];   // 612 f4 = 9792 B
    __shared__ float wmax[4];
    float* g = (float*)g4;

    const int b   = blockIdx.z;
    const int tx0 = blockIdx.x * TILE_W;         // multiple of 128
    const int ty0 = blockIdx.y * TILE_H;
    const int tid = threadIdx.x;                 // block = 256 flat

    const size_t HW = (size_t)IMG_H * IMG_W;
    const float4* base4 = (const float4*)(in + (size_t)b * NC * HW);

    // ---- Phase A: stage gray tile + halo into LDS with float4 loads ----
    // LDS col l (float) <-> global x = tx0 - 4 + l ; LDS row r <-> global y = ty0 - 1 + r
    const int tx0_4 = tx0 >> 2;
    #pragma unroll
    for (int k = 0; k < 3; ++k) {
        int idx = tid + k * 256;
        if (idx < LDS_ROWS * LDS_F4_W) {
            int row = idx / LDS_F4_W;
            int col = idx - row * LDS_F4_W;
            int gy  = ty0 + row - 1;
            int gx4 = tx0_4 + col - 1;
            float4 v = make_float4(0.f, 0.f, 0.f, 0.f);
            if (gy >= 0 && gy < IMG_H && gx4 >= 0 && gx4 < (IMG_W >> 2)) {
                const float4* p = base4 + (size_t)gy * (IMG_W >> 2) + gx4;
                float4 a = p[0];
                float4 c = p[PLANE_F4];
                float4 d = p[2 * PLANE_F4];
                v = make_float4((a.x + c.x + d.x) * (1.0f / 3.0f),
                                (a.y + c.y + d.y) * (1.0f / 3.0f),
                                (a.z + c.z + d.z) * (1.0f / 3.0f),
                                (a.w + c.w + d.w) * (1.0f / 3.0f));
            }
            g4[idx] = v;
        }
    }
    __syncthreads();

    // ---- Phase B: 8 scalar outputs per thread, stride-256 pixel mapping ----
    // pixel p in [0, 2048): oy = p>>7, ox = p&127. Consecutive lanes ->
    // consecutive LDS floats (conflict-free) + consecutive dword stores.
    float lmax = 0.0f;
    float* outb = out + (size_t)b * NC * HW;     // channel-0 plane as magnitude scratch

    #pragma unroll
    for (int k = 0; k < 8; ++k) {
        int p  = tid + k * 256;
        int oy = p >> 7;
        int ox = p & 127;
        const float* r0 = g + (oy    ) * LDS_F_W + ox + 3;  // gray row oy-1, cols ox-1..
        const float* r1 = g + (oy + 1) * LDS_F_W + ox + 3;
        const float* r2 = g + (oy + 2) * LDS_F_W + ox + 3;
        float a00 = r0[0], a01 = r0[1], a02 = r0[2];
        float a10 = r1[0],             a12 = r1[2];
        float a20 = r2[0], a21 = r2[1], a22 = r2[2];
        float sx = (a02 - a00) + 2.0f * (a12 - a10) + (a22 - a20);
        float sy = (a20 - a00) + 2.0f * (a21 - a01) + (a22 - a02);
        float mag = sqrtf(sx * sx + sy * sy);
        outb[(size_t)(ty0 + oy) * IMG_W + (tx0 + ox)] = mag;
        lmax = fmaxf(lmax, mag);
    }

    // Wave (64-lane) shuffle reduce, then 4-wave LDS reduce, then device atomicMax.
    #pragma unroll
    for (int off = 32; off > 0; off >>= 1)
        lmax = fmaxf(lmax, __shfl_down(lmax, off, 64));
    if ((tid & 63) == 0) wmax[tid >> 6] = lmax;
    __syncthreads();
    if (tid == 0) {
        float m = fmaxf(fmaxf(wmax[0], wmax[1]), fmaxf(wmax[2], wmax[3]));
        atomicMax(&maxbuf[b], __float_as_uint(m));   // mag >= 0: uint order == float order
    }
}

// Kernel 2: read magnitude from channel 0, normalize, broadcast to all 3 channels.
// 64 blocks per image; each thread owns 4 float4s; inv computed once.
__global__ __launch_bounds__(256) void normalize_kernel(
    float* __restrict__ out, const unsigned int* __restrict__ maxbuf)
{
    const size_t HW = (size_t)IMG_H * IMG_W;
    const int b     = blockIdx.x >> 6;           // image
    const int chunk = blockIdx.x & 63;           // 1024 f4 per chunk

    const float mx  = __uint_as_float(maxbuf[b]);
    const float inv = 1.0f / (mx + 1e-6f);

    float4* c0 = (float4*)(out + (size_t)b * NC * HW);
    float4* c1 = (float4*)(out + ((size_t)b * NC + 1) * HW);
    float4* c2 = (float4*)(out + ((size_t)b * NC + 2) * HW);

    #pragma unroll
    for (int k = 0; k < 4; ++k) {
        int i = chunk * 1024 + k * 256 + threadIdx.x;
        float4 m = c0[i];
        float4 v = make_float4(m.x * inv, m.y * inv, m.z * inv, m.w * inv);
        c0[i] = v;
        c1[i] = v;
        c2[i] = v;
    }
}

extern "C" void kernel_launch(void* const* d_in, const int* in_sizes, int n_in,
                              void* d_out, int out_size, void* d_ws, size_t ws_size,
                              hipStream_t stream)
{
    const float* in  = (const float*)d_in[0];
    float*       out = (float*)d_out;
    unsigned int* maxbuf = (unsigned int*)d_ws;  // 32 * 4 = 128 bytes

    hipMemsetAsync(maxbuf, 0, NB * sizeof(unsigned int), stream);

    dim3 grid1(IMG_W / TILE_W, IMG_H / TILE_H, NB);   // (4, 32, 32)
    sobel_mag_kernel<<<grid1, dim3(256, 1, 1), 0, stream>>>(in, out, maxbuf);

    normalize_kernel<<<dim3(NB * 64, 1, 1), dim3(256, 1, 1), 0, stream>>>(out, maxbuf);
}